// Round 3
// baseline (158.905 us; speedup 1.0000x reference)
//
#include <hip/hip_runtime.h>

typedef __attribute__((ext_vector_type(8))) short short8;
typedef __attribute__((ext_vector_type(4))) float f32x4;
typedef __attribute__((ext_vector_type(2))) unsigned long long u64x2;

#define NN 8192
#define FIN 128
#define FOUT 64
#define NT (NN / 64)          // 128 mask words per row
#define LRELU_ALPHA 0.2f

__device__ __forceinline__ unsigned short f2bf(float x) {
    unsigned u = __float_as_uint(x);
    unsigned r = (u + 0x7FFFu + ((u >> 16) & 1u)) >> 16;  // RNE
    return (unsigned short)r;
}

// ---------------------------------------------------------------------------
// Kernel 1: h = inp @ W ; s1 = h@a1 ; s2 = h@a2 ;
//   ht[f][i] = bf16(h[i][f]) ; e1v[i]=exp(s2_i) ; e2v[i]=exp(alpha*s2_i)
// Natural column order throughout (mask kernel emits natural bit order).
// ---------------------------------------------------------------------------
__global__ __launch_bounds__(256) void gat_prep(
    const float* __restrict__ inp, const float* __restrict__ W,
    const float* __restrict__ a,
    unsigned short* __restrict__ ht, float* __restrict__ s1, float* __restrict__ s2,
    float* __restrict__ e1v, float* __restrict__ e2v)
{
    __shared__ float Wl[FIN * FOUT];   // 32 KB
    __shared__ float il[4 * FIN];      // 2 KB
    const int t = threadIdx.x;
    const int i0 = blockIdx.x * 4;

    #pragma unroll
    for (int k = 0; k < (FIN * FOUT) / 256; ++k)
        Wl[t + 256 * k] = W[t + 256 * k];
    #pragma unroll
    for (int k = 0; k < (4 * FIN) / 256; ++k)
        il[t + 256 * k] = inp[(size_t)i0 * FIN + t + 256 * k];
    __syncthreads();

    const int r = t >> 6;        // local row 0..3
    const int f = t & 63;        // output feature
    float acc = 0.f;
    #pragma unroll 8
    for (int k = 0; k < FIN; ++k)
        acc = fmaf(il[r * FIN + k], Wl[k * FOUT + f], acc);

    float v1 = acc * a[f];
    float v2 = acc * a[FOUT + f];
    #pragma unroll
    for (int off = 32; off; off >>= 1) {
        v1 += __shfl_xor(v1, off, 64);
        v2 += __shfl_xor(v2, off, 64);
    }
    const int i = i0 + r;
    if (f == 0) {
        s1[i] = v1;
        s2[i] = v2;
        e1v[i] = __expf(v2);
        e2v[i] = __expf(LRELU_ALPHA * v2);
    }
    ht[(size_t)f * NN + i] = f2bf(acc);
}

// ---------------------------------------------------------------------------
// Kernel 2: s2max = max_j s2[j]
// ---------------------------------------------------------------------------
__global__ __launch_bounds__(1024) void gat_s2max(const float* __restrict__ s2,
                                                  float* __restrict__ s2m)
{
    __shared__ float red[16];
    float m = -1e30f;
    for (int idx = threadIdx.x; idx < NN; idx += 1024) m = fmaxf(m, s2[idx]);
    #pragma unroll
    for (int off = 32; off; off >>= 1) m = fmaxf(m, __shfl_xor(m, off, 64));
    if ((threadIdx.x & 63) == 0) red[threadIdx.x >> 6] = m;
    __syncthreads();
    if (threadIdx.x == 0) {
        float mm = red[0];
        #pragma unroll
        for (int k = 1; k < 16; ++k) mm = fmaxf(mm, red[k]);
        s2m[0] = mm;
    }
}

// ---------------------------------------------------------------------------
// Kernel 3: adj (int32, 256 MB) -> bitmask (1 bit/entry, 8 MB), natural order.
// 1 wave per row; lane l ballots col 64t+l. 4 tiles in flight for MLP.
// Pure HBM stream — target ~85% of peak.
// ---------------------------------------------------------------------------
__global__ __launch_bounds__(256) void gat_mask(const int* __restrict__ adj,
                                                unsigned long long* __restrict__ mask)
{
    const int i    = blockIdx.x * 4 + (threadIdx.x >> 6);   // row = global wave id
    const int lane = threadIdx.x & 63;
    const int* arow = adj + (size_t)i * NN + lane;
    unsigned long long* mrow = mask + (size_t)i * NT;

    for (int t = 0; t < NT; t += 4) {
        const int v0 = arow[(size_t)(t + 0) * 64];
        const int v1 = arow[(size_t)(t + 1) * 64];
        const int v2 = arow[(size_t)(t + 2) * 64];
        const int v3 = arow[(size_t)(t + 3) * 64];
        const unsigned long long b0 = __ballot(v0 > 0);
        const unsigned long long b1 = __ballot(v1 > 0);
        const unsigned long long b2 = __ballot(v2 > 0);
        const unsigned long long b3 = __ballot(v3 > 0);
        if (lane == 0) {
            u64x2 w01 = {b0, b1}, w23 = {b2, b3};
            *(u64x2*)(mrow + t)     = w01;
            *(u64x2*)(mrow + t + 2) = w23;
        }
    }
}

// ---------------------------------------------------------------------------
// Kernel 4 (hot): mask-driven attention, all operands L2-resident.
// Block: 256 = 4 waves x 16 rows. Grid: (128, JS).
// Per wave per 64-col tile: 1 u64 mask load, 2 MFMA K=32 steps,
// p = mask ? (x>0 ? c1*e1 : c2*e2) : 0 ; row-sum via ones-B MFMA.
// ---------------------------------------------------------------------------
__global__ __launch_bounds__(256, 4) void gat_attn(
    const unsigned long long* __restrict__ mask, const unsigned short* __restrict__ ht,
    const float* __restrict__ s1, const float* __restrict__ e1v,
    const float* __restrict__ e2v, const float* __restrict__ s2m,
    float* __restrict__ pacc, float* __restrict__ pl, int jlen)
{
    const int w    = threadIdx.x >> 6;   // wave 0..3 -> rows w*16..w*16+15
    const int lane = threadIdx.x & 63;
    const int lo   = lane & 15;          // A-frag row / B-frag col
    const int kg   = lane >> 4;          // k-group 0..3
    const int i0   = blockIdx.x * 64;
    const int i    = i0 + w * 16 + lo;   // this lane's attention row

    const float s1v = s1[i];
    const float mm  = s1v + s2m[0];
    const float Mi  = fmaxf(mm, LRELU_ALPHA * mm);      // >= max_j e_ij
    const float c1  = __expf(s1v - Mi);
    const float c2  = __expf(LRELU_ALPHA * s1v - Mi);
    const float Er  = __expf(-s1v);                     // x>0  <=>  e1 > Er

    const unsigned long long* mrow = mask + (size_t)i * NT;
    const int tstart = (blockIdx.y * jlen) >> 6;
    const int tend   = tstart + (jlen >> 6);

    f32x4 acc0 = {0.f,0.f,0.f,0.f}, acc1 = {0.f,0.f,0.f,0.f};
    f32x4 acc2 = {0.f,0.f,0.f,0.f}, acc3 = {0.f,0.f,0.f,0.f};
    f32x4 accl = {0.f,0.f,0.f,0.f};

    // all-ones bf16 B fragment (1.0 = 0x3F80) for the row-sum accumulator
    short8 ones;
    #pragma unroll
    for (int e = 0; e < 8; ++e) ones[e] = (short)0x3F80;

    unsigned long long mw = mrow[tstart];

    for (int t = tstart; t < tend; ++t) {
        const unsigned long long mcur = mw;
        if (t + 1 < tend) mw = mrow[t + 1];            // prefetch next mask word

        const int jc = t << 6;
        #pragma unroll
        for (int s = 0; s < 2; ++s) {
            const unsigned mb = (unsigned)(mcur >> (32 * s + 8 * kg)) & 0xffu;
            const int vg = jc + 32 * s + 8 * kg;
            const f32x4 E1a = *(const f32x4*)(e1v + vg);
            const f32x4 E1b = *(const f32x4*)(e1v + vg + 4);
            const f32x4 E2a = *(const f32x4*)(e2v + vg);
            const f32x4 E2b = *(const f32x4*)(e2v + vg + 4);

            short8 af;
            #pragma unroll
            for (int e = 0; e < 8; ++e) {
                const float e1 = (e < 4) ? E1a[e] : E1b[e - 4];
                const float e2 = (e < 4) ? E2a[e] : E2b[e - 4];
                float pv = (e1 > Er) ? c1 * e1 : c2 * e2;
                pv = ((mb >> e) & 1u) ? pv : 0.f;
                af[e] = (short)f2bf(pv);
            }

            const unsigned short* hb = ht + vg;
            const short8 b0 = *(const short8*)(hb + (size_t)(0 * 16 + lo) * NN);
            const short8 b1 = *(const short8*)(hb + (size_t)(1 * 16 + lo) * NN);
            const short8 b2 = *(const short8*)(hb + (size_t)(2 * 16 + lo) * NN);
            const short8 b3 = *(const short8*)(hb + (size_t)(3 * 16 + lo) * NN);

            acc0 = __builtin_amdgcn_mfma_f32_16x16x32_bf16(af, b0, acc0, 0, 0, 0);
            acc1 = __builtin_amdgcn_mfma_f32_16x16x32_bf16(af, b1, acc1, 0, 0, 0);
            acc2 = __builtin_amdgcn_mfma_f32_16x16x32_bf16(af, b2, acc2, 0, 0, 0);
            acc3 = __builtin_amdgcn_mfma_f32_16x16x32_bf16(af, b3, acc3, 0, 0, 0);
            accl = __builtin_amdgcn_mfma_f32_16x16x32_bf16(af, ones, accl, 0, 0, 0);
        }
    }

    // row sums: D[row][col] identical over col; lanes with lo==0 own rows kg*4+reg
    if (lo == 0) {
        float* plw = pl + (size_t)blockIdx.y * NN + i0 + w * 16;
        #pragma unroll
        for (int reg = 0; reg < 4; ++reg) plw[kg * 4 + reg] = accl[reg];
    }

    // C/D layout (m89-verified): col = lane&15, row = (lane>>4)*4 + reg
    float* pa = pacc + ((size_t)blockIdx.y * NN + i0 + w * 16) * FOUT;
    #pragma unroll
    for (int reg = 0; reg < 4; ++reg) {
        const int orow = kg * 4 + reg;
        pa[(size_t)orow * FOUT + 0 * 16 + lo] = acc0[reg];
        pa[(size_t)orow * FOUT + 1 * 16 + lo] = acc1[reg];
        pa[(size_t)orow * FOUT + 2 * 16 + lo] = acc2[reg];
        pa[(size_t)orow * FOUT + 3 * 16 + lo] = acc3[reg];
    }
}

// ---------------------------------------------------------------------------
// Kernel 5: sum partials over j-splits, normalize, elu.
// ---------------------------------------------------------------------------
__global__ __launch_bounds__(256) void gat_reduce(
    const float* __restrict__ pacc, const float* __restrict__ pl,
    float* __restrict__ out, int JS)
{
    const int t = blockIdx.x * 256 + threadIdx.x;   // t < 8192*64
    const int i = t >> 6;
    float l = 0.f, v = 0.f;
    for (int js = 0; js < JS; ++js) {
        l += pl[(size_t)js * NN + i];
        v += pacc[(size_t)js * NN * FOUT + t];
    }
    const float r = v / l;
    out[t] = r > 0.f ? r : expm1f(r);
}

// ---------------------------------------------------------------------------
extern "C" void kernel_launch(void* const* d_in, const int* in_sizes, int n_in,
                              void* d_out, int out_size, void* d_ws, size_t ws_size,
                              hipStream_t stream)
{
    const float* inp = (const float*)d_in[0];
    const int*   adj = (const int*)d_in[1];
    const float* W   = (const float*)d_in[2];
    const float* a   = (const float*)d_in[3];
    float* out = (float*)d_out;

    // workspace carve-up
    char* ws = (char*)d_ws;
    unsigned short* ht = (unsigned short*)ws; ws += (size_t)FOUT * NN * 2;   // 1 MB
    unsigned long long* mask = (unsigned long long*)ws; ws += (size_t)NN * NT * 8;  // 8 MB
    float* s1  = (float*)ws; ws += (size_t)NN * 4;
    float* s2  = (float*)ws; ws += (size_t)NN * 4;
    float* e1v = (float*)ws; ws += (size_t)NN * 4;
    float* e2v = (float*)ws; ws += (size_t)NN * 4;
    float* s2m = (float*)ws; ws += 256;
    const size_t fixed = (size_t)(ws - (char*)d_ws);

    int JS = 8;
    while (JS > 1 && fixed + (size_t)JS * NN * 4ull * (FOUT + 1) > ws_size) JS >>= 1;
    const int jlen = NN / JS;

    float* pl   = (float*)ws; ws += (size_t)JS * NN * 4;
    float* pacc = (float*)ws;

    gat_prep  <<<NN / 4, 256, 0, stream>>>(inp, W, a, ht, s1, s2, e1v, e2v);
    gat_s2max <<<1, 1024, 0, stream>>>(s2, s2m);
    gat_mask  <<<NN / 4, 256, 0, stream>>>(adj, mask);
    gat_attn  <<<dim3(NN / 64, JS), 256, 0, stream>>>(mask, ht, s1, e1v, e2v, s2m, pacc, pl, jlen);
    gat_reduce<<<(NN * FOUT) / 256, 256, 0, stream>>>(pacc, pl, out, JS);
}

// Round 4
// 151.232 us; speedup vs baseline: 1.0507x; 1.0507x over previous
//
#include <hip/hip_runtime.h>

typedef __attribute__((ext_vector_type(8))) short short8;
typedef __attribute__((ext_vector_type(4))) float f32x4;
typedef __attribute__((ext_vector_type(4))) int   i32x4;
typedef unsigned long long u64;
typedef __attribute__((ext_vector_type(2))) u64 u64x2;

#define NN 8192
#define FIN 128
#define FOUT 64
#define NT (NN / 64)          // 128 mask words per row
#define LRELU_ALPHA 0.2f

__device__ __forceinline__ unsigned short f2bf(float x) {
    unsigned u = __float_as_uint(x);
    unsigned r = (u + 0x7FFFu + ((u >> 16) & 1u)) >> 16;  // RNE
    return (unsigned short)r;
}

// dwordx4-ballot column permutation within each 256-col group:
// natural col c = 256g + 4l + e  ->  virtual col v = 256g + 64e + l
__device__ __forceinline__ unsigned vcol_of(unsigned c) {
    return (c & ~255u) | ((c & 3u) << 6) | ((c & 255u) >> 2);
}

// ---------------------------------------------------------------------------
// Kernel 1: h = inp @ W ; s1 = h@a1 ; s2 = h@a2 ;
//   ht[f][vcol(i)] = bf16(h[i][f]) ; e1v[vcol]=exp(s2) ; e2v[vcol]=exp(a*s2)
// ---------------------------------------------------------------------------
__global__ __launch_bounds__(256) void gat_prep(
    const float* __restrict__ inp, const float* __restrict__ W,
    const float* __restrict__ a,
    unsigned short* __restrict__ ht, float* __restrict__ s1, float* __restrict__ s2,
    float* __restrict__ e1v, float* __restrict__ e2v)
{
    __shared__ float Wl[FIN * FOUT];   // 32 KB
    __shared__ float il[4 * FIN];      // 2 KB
    const int t = threadIdx.x;
    const int i0 = blockIdx.x * 4;

    #pragma unroll
    for (int k = 0; k < (FIN * FOUT) / 256; ++k)
        Wl[t + 256 * k] = W[t + 256 * k];
    #pragma unroll
    for (int k = 0; k < (4 * FIN) / 256; ++k)
        il[t + 256 * k] = inp[(size_t)i0 * FIN + t + 256 * k];
    __syncthreads();

    const int r = t >> 6;        // local row 0..3
    const int f = t & 63;        // output feature
    float acc = 0.f;
    #pragma unroll 8
    for (int k = 0; k < FIN; ++k)
        acc = fmaf(il[r * FIN + k], Wl[k * FOUT + f], acc);

    float v1 = acc * a[f];
    float v2 = acc * a[FOUT + f];
    #pragma unroll
    for (int off = 32; off; off >>= 1) {
        v1 += __shfl_xor(v1, off, 64);
        v2 += __shfl_xor(v2, off, 64);
    }
    const int i = i0 + r;
    const unsigned vc = vcol_of((unsigned)i);
    if (f == 0) {
        s1[i] = v1;
        s2[i] = v2;
        e1v[vc] = __expf(v2);
        e2v[vc] = __expf(LRELU_ALPHA * v2);
    }
    ht[(size_t)f * NN + vc] = f2bf(acc);
}

// ---------------------------------------------------------------------------
// Kernel 2: s2max = max_j s2[j]
// ---------------------------------------------------------------------------
__global__ __launch_bounds__(1024) void gat_s2max(const float* __restrict__ s2,
                                                  float* __restrict__ s2m)
{
    __shared__ float red[16];
    float m = -1e30f;
    for (int idx = threadIdx.x; idx < NN; idx += 1024) m = fmaxf(m, s2[idx]);
    #pragma unroll
    for (int off = 32; off; off >>= 1) m = fmaxf(m, __shfl_xor(m, off, 64));
    if ((threadIdx.x & 63) == 0) red[threadIdx.x >> 6] = m;
    __syncthreads();
    if (threadIdx.x == 0) {
        float mm = red[0];
        #pragma unroll
        for (int k = 1; k < 16; ++k) mm = fmaxf(mm, red[k]);
        s2m[0] = mm;
    }
}

// ---------------------------------------------------------------------------
// Kernel 3: adj (256 MB int32) -> bitmask (8 MB), virtual-col bit order.
// Each wave: TWO rows (i, i+4096), dwordx4 loads, 8 KB issued per iteration
// before ballots consume it (deep MLP: >=64 KB/CU in flight).
// Word 4t+e of row: bit l = adj[row][256t + 4l + e] > 0.
// ---------------------------------------------------------------------------
__global__ __launch_bounds__(256) void gat_mask(const int* __restrict__ adj,
                                                u64* __restrict__ mask)
{
    const int wid  = blockIdx.x * 4 + (threadIdx.x >> 6);
    const int lane = threadIdx.x & 63;
    const int iA = wid, iB = wid + NN / 2;
    const int* pA = adj + (size_t)iA * NN + lane * 4;
    const int* pB = adj + (size_t)iB * NN + lane * 4;
    u64* mA = mask + (size_t)iA * NT;
    u64* mB = mask + (size_t)iB * NT;

    for (int t = 0; t < 32; t += 4) {
        i32x4 a[4], b[4];
        #pragma unroll
        for (int k = 0; k < 4; ++k) a[k] = *(const i32x4*)(pA + (size_t)(t + k) * 256);
        #pragma unroll
        for (int k = 0; k < 4; ++k) b[k] = *(const i32x4*)(pB + (size_t)(t + k) * 256);

        u64 wa[16], wb[16];
        #pragma unroll
        for (int k = 0; k < 4; ++k) {
            #pragma unroll
            for (int e = 0; e < 4; ++e) {
                wa[k * 4 + e] = __ballot(a[k][e] > 0);
                wb[k * 4 + e] = __ballot(b[k][e] > 0);
            }
        }
        if (lane == 0) {
            #pragma unroll
            for (int q = 0; q < 8; ++q) {
                u64x2 va = {wa[2 * q], wa[2 * q + 1]};
                u64x2 vb = {wb[2 * q], wb[2 * q + 1]};
                *(u64x2*)(mA + 4 * t + 2 * q) = va;
                *(u64x2*)(mB + 4 * t + 2 * q) = vb;
            }
        }
    }
}

// ---------------------------------------------------------------------------
// Kernel 4 (hot): mask-driven attention, all operands L2-resident.
// Identical logic to R3 (virtual col space); af pack via v_cvt_pk_bf16_f32.
// Block: 256 = 4 waves x 16 rows. Grid: (128, JS).
// ---------------------------------------------------------------------------
__global__ __launch_bounds__(256, 4) void gat_attn(
    const u64* __restrict__ mask, const unsigned short* __restrict__ ht,
    const float* __restrict__ s1, const float* __restrict__ e1v,
    const float* __restrict__ e2v, const float* __restrict__ s2m,
    float* __restrict__ pacc, float* __restrict__ pl, int jlen)
{
    const int w    = threadIdx.x >> 6;   // wave 0..3 -> rows w*16..w*16+15
    const int lane = threadIdx.x & 63;
    const int lo   = lane & 15;          // A-frag row / B-frag col
    const int kg   = lane >> 4;          // k-group 0..3
    const int i0   = blockIdx.x * 64;
    const int i    = i0 + w * 16 + lo;   // this lane's attention row

    const float s1v = s1[i];
    const float mm  = s1v + s2m[0];
    const float Mi  = fmaxf(mm, LRELU_ALPHA * mm);      // >= max_j e_ij
    const float c1  = __expf(s1v - Mi);
    const float c2  = __expf(LRELU_ALPHA * s1v - Mi);
    const float Er  = __expf(-s1v);                     // x>0  <=>  e1 > Er

    const u64* mrow = mask + (size_t)i * NT;
    const int tstart = (blockIdx.y * jlen) >> 6;
    const int tend   = tstart + (jlen >> 6);

    f32x4 acc0 = {0.f,0.f,0.f,0.f}, acc1 = {0.f,0.f,0.f,0.f};
    f32x4 acc2 = {0.f,0.f,0.f,0.f}, acc3 = {0.f,0.f,0.f,0.f};
    f32x4 accl = {0.f,0.f,0.f,0.f};

    // all-ones bf16 B fragment (1.0 = 0x3F80) for the row-sum accumulator
    short8 ones;
    #pragma unroll
    for (int e = 0; e < 8; ++e) ones[e] = (short)0x3F80;

    u64 mw = mrow[tstart];

    for (int t = tstart; t < tend; ++t) {
        const u64 mcur = mw;
        if (t + 1 < tend) mw = mrow[t + 1];            // prefetch next mask word

        const int jc = t << 6;
        #pragma unroll
        for (int s = 0; s < 2; ++s) {
            const unsigned mb = (unsigned)(mcur >> (32 * s + 8 * kg)) & 0xffu;
            const int vg = jc + 32 * s + 8 * kg;
            const f32x4 E1a = *(const f32x4*)(e1v + vg);
            const f32x4 E1b = *(const f32x4*)(e1v + vg + 4);
            const f32x4 E2a = *(const f32x4*)(e2v + vg);
            const f32x4 E2b = *(const f32x4*)(e2v + vg + 4);

            float p[8];
            #pragma unroll
            for (int e = 0; e < 8; ++e) {
                const float e1 = (e < 4) ? E1a[e] : E1b[e - 4];
                const float e2 = (e < 4) ? E2a[e] : E2b[e - 4];
                float pv = (e1 > Er) ? c1 * e1 : c2 * e2;
                pv = ((mb >> e) & 1u) ? pv : 0.f;
                p[e] = pv;
            }
            union { short8 s8; unsigned u[4]; } afu;
            #pragma unroll
            for (int q = 0; q < 4; ++q) {
                unsigned rr;
                asm("v_cvt_pk_bf16_f32 %0, %1, %2" : "=v"(rr) : "v"(p[2 * q]), "v"(p[2 * q + 1]));
                afu.u[q] = rr;
            }
            const short8 af = afu.s8;

            const unsigned short* hb = ht + vg;
            const short8 b0 = *(const short8*)(hb + (size_t)(0 * 16 + lo) * NN);
            const short8 b1 = *(const short8*)(hb + (size_t)(1 * 16 + lo) * NN);
            const short8 b2 = *(const short8*)(hb + (size_t)(2 * 16 + lo) * NN);
            const short8 b3 = *(const short8*)(hb + (size_t)(3 * 16 + lo) * NN);

            acc0 = __builtin_amdgcn_mfma_f32_16x16x32_bf16(af, b0, acc0, 0, 0, 0);
            acc1 = __builtin_amdgcn_mfma_f32_16x16x32_bf16(af, b1, acc1, 0, 0, 0);
            acc2 = __builtin_amdgcn_mfma_f32_16x16x32_bf16(af, b2, acc2, 0, 0, 0);
            acc3 = __builtin_amdgcn_mfma_f32_16x16x32_bf16(af, b3, acc3, 0, 0, 0);
            accl = __builtin_amdgcn_mfma_f32_16x16x32_bf16(af, ones, accl, 0, 0, 0);
        }
    }

    // row sums: D[row][col] identical over col; lanes with lo==0 own rows kg*4+reg
    if (lo == 0) {
        float* plw = pl + (size_t)blockIdx.y * NN + i0 + w * 16;
        #pragma unroll
        for (int reg = 0; reg < 4; ++reg) plw[kg * 4 + reg] = accl[reg];
    }

    // C/D layout (m89-verified): col = lane&15, row = (lane>>4)*4 + reg
    float* pa = pacc + ((size_t)blockIdx.y * NN + i0 + w * 16) * FOUT;
    #pragma unroll
    for (int reg = 0; reg < 4; ++reg) {
        const int orow = kg * 4 + reg;
        pa[(size_t)orow * FOUT + 0 * 16 + lo] = acc0[reg];
        pa[(size_t)orow * FOUT + 1 * 16 + lo] = acc1[reg];
        pa[(size_t)orow * FOUT + 2 * 16 + lo] = acc2[reg];
        pa[(size_t)orow * FOUT + 3 * 16 + lo] = acc3[reg];
    }
}

// ---------------------------------------------------------------------------
// Kernel 5: sum partials over j-splits, normalize, elu.
// ---------------------------------------------------------------------------
__global__ __launch_bounds__(256) void gat_reduce(
    const float* __restrict__ pacc, const float* __restrict__ pl,
    float* __restrict__ out, int JS)
{
    const int t = blockIdx.x * 256 + threadIdx.x;   // t < 8192*64
    const int i = t >> 6;
    float l = 0.f, v = 0.f;
    for (int js = 0; js < JS; ++js) {
        l += pl[(size_t)js * NN + i];
        v += pacc[(size_t)js * NN * FOUT + t];
    }
    const float r = v / l;
    out[t] = r > 0.f ? r : expm1f(r);
}

// ---------------------------------------------------------------------------
extern "C" void kernel_launch(void* const* d_in, const int* in_sizes, int n_in,
                              void* d_out, int out_size, void* d_ws, size_t ws_size,
                              hipStream_t stream)
{
    const float* inp = (const float*)d_in[0];
    const int*   adj = (const int*)d_in[1];
    const float* W   = (const float*)d_in[2];
    const float* a   = (const float*)d_in[3];
    float* out = (float*)d_out;

    // workspace carve-up
    char* ws = (char*)d_ws;
    unsigned short* ht = (unsigned short*)ws; ws += (size_t)FOUT * NN * 2;   // 1 MB
    u64* mask = (u64*)ws; ws += (size_t)NN * NT * 8;                         // 8 MB
    float* s1  = (float*)ws; ws += (size_t)NN * 4;
    float* s2  = (float*)ws; ws += (size_t)NN * 4;
    float* e1v = (float*)ws; ws += (size_t)NN * 4;
    float* e2v = (float*)ws; ws += (size_t)NN * 4;
    float* s2m = (float*)ws; ws += 256;
    const size_t fixed = (size_t)(ws - (char*)d_ws);

    int JS = 8;
    while (JS > 1 && fixed + (size_t)JS * NN * 4ull * (FOUT + 1) > ws_size) JS >>= 1;
    const int jlen = NN / JS;

    float* pl   = (float*)ws; ws += (size_t)JS * NN * 4;
    float* pacc = (float*)ws;

    gat_mask  <<<NN / 8, 256, 0, stream>>>(adj, mask);
    gat_prep  <<<NN / 4, 256, 0, stream>>>(inp, W, a, ht, s1, s2, e1v, e2v);
    gat_s2max <<<1, 1024, 0, stream>>>(s2, s2m);
    gat_attn  <<<dim3(NN / 64, JS), 256, 0, stream>>>(mask, ht, s1, e1v, e2v, s2m, pacc, pl, jlen);
    gat_reduce<<<(NN * FOUT) / 256, 256, 0, stream>>>(pacc, pl, out, JS);
}